// Round 3
// baseline (334.674 us; speedup 1.0000x reference)
//
#include <hip/hip_runtime.h>

typedef _Float16 half8  __attribute__((ext_vector_type(8)));
typedef float    floatx4 __attribute__((ext_vector_type(4)));

#define N_NODES 50000
#define N_EDGES 800000
#define SLOPE 0.05f

// ---- workspace layout (bytes) ----
// xh:  fp16 [N_NODES][64]   = fp16(x)           (gather table: 128 B/row, 6.4 MB)
// w0t: fp16 [128][64]       w0t[n][k] = W0[k][n]
// wt1: fp16 [128][128]      wt1[n][k] = W1[k][n]
// wt2: fp16 [64][128]       wt2[n][k] = W2[k][n]
// b0,b1,b2: fp32
#define WS_XH  0ull
#define WS_W0  (WS_XH + (size_t)N_NODES * 64 * 2)
#define WS_W1  (WS_W0 + 128 * 64 * 2)
#define WS_W2  (WS_W1 + 128 * 128 * 2)
#define WS_B0  (WS_W2 + 64 * 128 * 2)
#define WS_B1  (WS_B0 + 128 * 4)
#define WS_B2  (WS_B1 + 128 * 4)

#define HC_STRIDE 40            // 32 + 8 fp16 pad (proven exchange layout)
#define XCONV_BLOCKS 782        // ceil(50000*64 / (512*8))
#define PREP_BLOCKS (XCONV_BLOCKS + 65)
#define EDGE_BLOCKS 1563        // ceil(800000/512); last block runs tile0 only

__device__ __forceinline__ float leaky(float t) { return t >= 0.f ? t : SLOPE * t; }

// ---------------- kernel 1: x->fp16 convert + weight transpose ----------------
__global__ void prep_kernel(const float* __restrict__ x,
                            const float* __restrict__ W0, const float* __restrict__ W1,
                            const float* __restrict__ W2, const float* __restrict__ b0,
                            const float* __restrict__ b1, const float* __restrict__ b2,
                            unsigned char* __restrict__ ws) {
    const int b = blockIdx.x;
    if (b < XCONV_BLOCKS) {                     // x [50000][64] fp32 -> xh fp16
        _Float16* xh = (_Float16*)(ws + WS_XH);
        const int i = (b * 512 + threadIdx.x) * 8;
        if (i < N_NODES * 64) {
            floatx4 u0 = *(const floatx4*)(x + i);
            floatx4 u1 = *(const floatx4*)(x + i + 4);
            half8 h;
            #pragma unroll
            for (int j = 0; j < 4; ++j) { h[j] = (_Float16)u0[j]; h[4 + j] = (_Float16)u1[j]; }
            *(half8*)(xh + i) = h;
        }
        return;
    }
    const int t = (b - XCONV_BLOCKS) * 512 + threadIdx.x;
    _Float16* w0t = (_Float16*)(ws + WS_W0);
    _Float16* wt1 = (_Float16*)(ws + WS_W1);
    _Float16* wt2 = (_Float16*)(ws + WS_W2);
    if (t < 8192) {                             // W0 [64][128] -> w0t[n][k]
        int k = t >> 7, n = t & 127;
        w0t[n * 64 + k] = (_Float16)W0[k * 128 + n];
    } else if (t < 24576) {                     // W1 [128][128] -> wt1[n][k]
        int i2 = t - 8192, k = i2 >> 7, n = i2 & 127;
        wt1[n * 128 + k] = (_Float16)W1[k * 128 + n];
    } else if (t < 32768) {                     // W2 [128][64] -> wt2[n][k]
        int i2 = t - 24576, k = i2 >> 6, n = i2 & 63;
        wt2[n * 128 + k] = (_Float16)W2[k * 64 + n];
    } else if (t < 33088) {
        int i2 = t - 32768;
        if (i2 < 128) ((float*)(ws + WS_B0))[i2] = b0[i2];
        else if (i2 < 256) ((float*)(ws + WS_B1))[i2 - 128] = b1[i2 - 128];
        else ((float*)(ws + WS_B2))[i2 - 256] = b2[i2 - 256];
    }
}

// ---- one 32-edge-per-wave tile: 3-layer MLP from prebuilt layer-0 A-frags ----
__device__ __forceinline__ void mlp_tile(const half8 a0[2][2], const int base,
        const _Float16* __restrict__ w0s, const _Float16* __restrict__ w1s,
        const _Float16* __restrict__ w2s, _Float16* __restrict__ hw,
        const float* __restrict__ b0s, const float* __restrict__ b1s,
        const float* __restrict__ b2s, float* __restrict__ out,
        const int cl, const int q, const int swz) {
    // ---- layer 0: h0 chunks n=2kk,2kk+1 -> hc round trip -> a1[g][kk] A-frags
    half8 a1[2][4];
    #pragma unroll
    for (int kk = 0; kk < 4; ++kk) {
        const int nA = 2 * kk, nB = 2 * kk + 1;
        half8 wA0 = *(const half8*)&w0s[((nA * 16 + cl) * 64 + q * 8) ^ swz];
        half8 wA1 = *(const half8*)&w0s[((nA * 16 + cl) * 64 + 32 + q * 8) ^ swz];
        half8 wB0 = *(const half8*)&w0s[((nB * 16 + cl) * 64 + q * 8) ^ swz];
        half8 wB1 = *(const half8*)&w0s[((nB * 16 + cl) * 64 + 32 + q * 8) ^ swz];
        const float bbA = b0s[nA * 16 + cl], bbB = b0s[nB * 16 + cl];
        #pragma unroll
        for (int g = 0; g < 2; ++g) {       // sequential hc reuse (per-wave, lgkm-ordered)
            floatx4 cA = {0.f, 0.f, 0.f, 0.f}, cB = {0.f, 0.f, 0.f, 0.f};
            cA = __builtin_amdgcn_mfma_f32_16x16x32_f16(a0[g][0], wA0, cA, 0, 0, 0);
            cA = __builtin_amdgcn_mfma_f32_16x16x32_f16(a0[g][1], wA1, cA, 0, 0, 0);
            cB = __builtin_amdgcn_mfma_f32_16x16x32_f16(a0[g][0], wB0, cB, 0, 0, 0);
            cB = __builtin_amdgcn_mfma_f32_16x16x32_f16(a0[g][1], wB1, cB, 0, 0, 0);
            #pragma unroll
            for (int rr = 0; rr < 4; ++rr) {   // C/D: row(edge)=q*4+rr, col=cl
                hw[(q * 4 + rr) * HC_STRIDE + cl]      = (_Float16)leaky(cA[rr] + bbA);
                hw[(q * 4 + rr) * HC_STRIDE + 16 + cl] = (_Float16)leaky(cB[rr] + bbB);
            }
            a1[g][kk] = *(const half8*)&hw[cl * HC_STRIDE + q * 8];
        }
    }

    // ---- layers 1+2, interleaved by 32-col k-chunks; weight frags shared by both groups
    floatx4 acc2[2][4];
    #pragma unroll
    for (int g = 0; g < 2; ++g)
        #pragma unroll
        for (int n2 = 0; n2 < 4; ++n2) acc2[g][n2] = (floatx4){0.f, 0.f, 0.f, 0.f};

    #pragma unroll
    for (int ks = 0; ks < 4; ++ks) {
        const int nA = 2 * ks, nB = 2 * ks + 1;
        floatx4 cA0 = {0.f,0.f,0.f,0.f}, cA1 = {0.f,0.f,0.f,0.f};
        floatx4 cB0 = {0.f,0.f,0.f,0.f}, cB1 = {0.f,0.f,0.f,0.f};
        #pragma unroll
        for (int kk = 0; kk < 4; ++kk) {
            half8 b = *(const half8*)&w1s[((nA * 16 + cl) * 128 + kk * 32 + q * 8) ^ swz];
            cA0 = __builtin_amdgcn_mfma_f32_16x16x32_f16(a1[0][kk], b, cA0, 0, 0, 0);
            cA1 = __builtin_amdgcn_mfma_f32_16x16x32_f16(a1[1][kk], b, cA1, 0, 0, 0);
        }
        #pragma unroll
        for (int kk = 0; kk < 4; ++kk) {
            half8 b = *(const half8*)&w1s[((nB * 16 + cl) * 128 + kk * 32 + q * 8) ^ swz];
            cB0 = __builtin_amdgcn_mfma_f32_16x16x32_f16(a1[0][kk], b, cB0, 0, 0, 0);
            cB1 = __builtin_amdgcn_mfma_f32_16x16x32_f16(a1[1][kk], b, cB1, 0, 0, 0);
        }
        const float bbA = b1s[nA * 16 + cl], bbB = b1s[nB * 16 + cl];
        half8 a2[2];
        #pragma unroll
        for (int g = 0; g < 2; ++g) {       // sequential hc reuse again
            const floatx4 cc0 = g ? cA1 : cA0;
            const floatx4 cc1 = g ? cB1 : cB0;
            #pragma unroll
            for (int rr = 0; rr < 4; ++rr) {
                hw[(q * 4 + rr) * HC_STRIDE + cl]      = (_Float16)leaky(cc0[rr] + bbA);
                hw[(q * 4 + rr) * HC_STRIDE + 16 + cl] = (_Float16)leaky(cc1[rr] + bbB);
            }
            a2[g] = *(const half8*)&hw[cl * HC_STRIDE + q * 8];
        }
        #pragma unroll
        for (int n2 = 0; n2 < 4; ++n2) {
            half8 b = *(const half8*)&w2s[((n2 * 16 + cl) * 128 + ks * 32 + q * 8) ^ swz];
            // swapped operands: lane holds 4 CONSECUTIVE output features for edge cl
            acc2[0][n2] = __builtin_amdgcn_mfma_f32_16x16x32_f16(b, a2[0], acc2[0][n2], 0, 0, 0);
            acc2[1][n2] = __builtin_amdgcn_mfma_f32_16x16x32_f16(b, a2[1], acc2[1][n2], 0, 0, 0);
        }
    }

    // epilogue: register-direct float4 stores (16 edges x full 64B lines per instr;
    // normal stores -- L2 write-combines; nt measured 1.88x write amplification)
    #pragma unroll
    for (int n2 = 0; n2 < 4; ++n2) {
        floatx4 bb = *(const floatx4*)&b2s[n2 * 16 + q * 4];
        #pragma unroll
        for (int g = 0; g < 2; ++g) {
            floatx4 o;
            #pragma unroll
            for (int rr = 0; rr < 4; ++rr) o[rr] = leaky(acc2[g][n2][rr] + bb[rr]);
            *(floatx4*)(out + (size_t)(base + g * 16 + cl) * 64 + n2 * 16 + q * 4) = o;
        }
    }
}

// ---------------- kernel 2: per-edge fused 3-layer MLP, 2 tiles/block ----------------
// 8 waves; each wave owns 32 edges/tile (two 16-edge A-frag groups sharing every
// weight-fragment LDS read). Tile-1 index loads issue at kernel top and tile-1
// GATHERS issue before tile-0 compute -- HBM gather latency hides under the
// 3-layer MFMA phase. Weights staged once per block (half the round-2 staging).
__global__ __launch_bounds__(512, 4) void edge_kernel(const int* __restrict__ ei,
                                                      const unsigned char* __restrict__ ws,
                                                      float* __restrict__ out) {
    // weight tiles unpadded, XOR-swizzled (half_idx ^= (row&7)<<3)
    __shared__ __align__(16) _Float16 w0s[128 * 64];          // 16384 B
    __shared__ __align__(16) _Float16 w1s[128 * 128];         // 32768 B
    __shared__ __align__(16) _Float16 w2s[64 * 128];          // 16384 B
    __shared__ __align__(16) _Float16 hc[8][16 * HC_STRIDE];  // 10240 B (per-wave)
    __shared__ __align__(16) float b0s[128], b1s[128], b2s[64];
    // total 77056 B -> 2 blocks/CU (16 waves/CU)

    const _Float16* __restrict__ xh  = (const _Float16*)(ws + WS_XH);
    const _Float16* __restrict__ w0g = (const _Float16*)(ws + WS_W0);
    const _Float16* __restrict__ w1g = (const _Float16*)(ws + WS_W1);
    const _Float16* __restrict__ w2g = (const _Float16*)(ws + WS_W2);

    const int wave = threadIdx.x >> 6, lane = threadIdx.x & 63;
    const int cl = lane & 15, q = lane >> 4;
    const int tbase = blockIdx.x * 512;
    const bool has1 = (tbase + 256) < N_EDGES;      // block-uniform
    const int base0 = tbase + wave * 32;
    const int base1 = tbase + 256 + wave * 32;

    // ---- ALL edge indices first (independent loads, issue together)
    const int r0 = base0 + cl;
    const int s00 = ei[r0], d00 = ei[N_EDGES + r0];
    const int s01 = ei[r0 + 16], d01 = ei[N_EDGES + r0 + 16];
    int s10 = 0, d10 = 0, s11 = 0, d11 = 0;
    if (has1) {
        const int r1 = base1 + cl;
        s10 = ei[r1]; d10 = ei[N_EDGES + r1];
        s11 = ei[r1 + 16]; d11 = ei[N_EDGES + r1 + 16];
    }

    // ---- tile-0 gathers: latency hides under weight staging
    const _Float16* ps0 = xh + (size_t)s00 * 64 + q * 8;
    const _Float16* pd0 = xh + (size_t)d00 * 64 + q * 8;
    const _Float16* ps1 = xh + (size_t)s01 * 64 + q * 8;
    const _Float16* pd1 = xh + (size_t)d01 * 64 + q * 8;
    half8 us00 = *(const half8*)(ps0);  half8 us01 = *(const half8*)(ps0 + 32);
    half8 ud00 = *(const half8*)(pd0);  half8 ud01 = *(const half8*)(pd0 + 32);
    half8 us10 = *(const half8*)(ps1);  half8 us11 = *(const half8*)(ps1 + 32);
    half8 ud10 = *(const half8*)(pd1);  half8 ud11 = *(const half8*)(pd1 + 32);

    {   // stage swizzled weights ONCE per block (reads hit L2 -- weights hot)
        const int t = threadIdx.x;
        #pragma unroll
        for (int it = 0; it < 4; ++it) {
            int c = t + it * 512, row = c >> 4, cc = c & 15;
            int dst = (row * 128 + cc * 8) ^ ((row & 7) << 3);
            *(half8*)&w1s[dst] = *(const half8*)&w1g[row * 128 + cc * 8];
        }
        #pragma unroll
        for (int it = 0; it < 2; ++it) {
            int c = t + it * 512, row = c >> 4, cc = c & 15;
            int dst = (row * 128 + cc * 8) ^ ((row & 7) << 3);
            *(half8*)&w2s[dst] = *(const half8*)&w2g[row * 128 + cc * 8];
        }
        #pragma unroll
        for (int it = 0; it < 2; ++it) {
            int c = t + it * 512, row = c >> 3, cc = c & 7;
            int dst = (row * 64 + cc * 8) ^ ((row & 7) << 3);
            *(half8*)&w0s[dst] = *(const half8*)&w0g[row * 64 + cc * 8];
        }
        if (t < 128) { b0s[t] = *(const float*)(ws + WS_B0 + t * 4);
                       b1s[t] = *(const float*)(ws + WS_B1 + t * 4); }
        else if (t < 192) b2s[t - 128] = *(const float*)(ws + WS_B2 + (size_t)(t - 128) * 4);
    }
    __syncthreads();

    // e = xh[s] + xh[d] (fp16) directly as A-frags: A[m=cl edge][k = ks*32 + q*8 + j]
    half8 a0[2][2];
    a0[0][0] = us00 + ud00;  a0[0][1] = us01 + ud01;
    a0[1][0] = us10 + ud10;  a0[1][1] = us11 + ud11;

    // ---- issue tile-1 gathers NOW; ~500cy HBM latency hides under tile-0 compute
    half8 t1[8];
    if (has1) {
        const _Float16* qs0 = xh + (size_t)s10 * 64 + q * 8;
        const _Float16* qd0 = xh + (size_t)d10 * 64 + q * 8;
        const _Float16* qs1 = xh + (size_t)s11 * 64 + q * 8;
        const _Float16* qd1 = xh + (size_t)d11 * 64 + q * 8;
        t1[0] = *(const half8*)(qs0);  t1[1] = *(const half8*)(qs0 + 32);
        t1[2] = *(const half8*)(qd0);  t1[3] = *(const half8*)(qd0 + 32);
        t1[4] = *(const half8*)(qs1);  t1[5] = *(const half8*)(qs1 + 32);
        t1[6] = *(const half8*)(qd1);  t1[7] = *(const half8*)(qd1 + 32);
    }

    const int swz = (cl & 7) << 3;
    _Float16* hw = &hc[wave][0];

    mlp_tile(a0, base0, w0s, w1s, w2s, hw, b0s, b1s, b2s, out, cl, q, swz);

    if (has1) {
        half8 a0b[2][2];
        a0b[0][0] = t1[0] + t1[2];  a0b[0][1] = t1[1] + t1[3];
        a0b[1][0] = t1[4] + t1[6];  a0b[1][1] = t1[5] + t1[7];
        mlp_tile(a0b, base1, w0s, w1s, w2s, hw, b0s, b1s, b2s, out, cl, q, swz);
    }
}

extern "C" void kernel_launch(void* const* d_in, const int* in_sizes, int n_in,
                              void* d_out, int out_size, void* d_ws, size_t ws_size,
                              hipStream_t stream) {
    const float* x  = (const float*)d_in[0];
    const int*   ei = (const int*)d_in[1];     // int inputs arrive as int32
    const float* W0 = (const float*)d_in[2];
    const float* b0 = (const float*)d_in[3];
    const float* W1 = (const float*)d_in[4];
    const float* b1 = (const float*)d_in[5];
    const float* W2 = (const float*)d_in[6];
    const float* b2 = (const float*)d_in[7];
    float* out = (float*)d_out;
    unsigned char* ws = (unsigned char*)d_ws;

    prep_kernel<<<PREP_BLOCKS, 512, 0, stream>>>(x, W0, W1, W2, b0, b1, b2, ws);
    edge_kernel<<<EDGE_BLOCKS, 512, 0, stream>>>(ei, ws, out);
}

// Round 4
// 286.450 us; speedup vs baseline: 1.1684x; 1.1684x over previous
//
#include <hip/hip_runtime.h>

typedef _Float16 half8  __attribute__((ext_vector_type(8)));
typedef float    floatx4 __attribute__((ext_vector_type(4)));

#define N_NODES 50000
#define N_EDGES 800000
#define SLOPE 0.05f

// ---- workspace layout (bytes) ----
// xh:  fp16 [N_NODES][64] = fp16(x)        (gather table: 128 B/row, 6.4 MB)
// wc:  fp16 [32768]  PRE-SWIZZLED weight block, laid out exactly as the edge
//      kernel's unified LDS image (64 KB = 64 chunks of 1 KB):
//        halves [    0,16384): Wt1[n][k^swz(n)]  n<128, k<128  (swz(n)=(n&7)<<3)
//        halves [16384,24576): Wt2[n][k^swz(n)]  n<64,  k<128
//        halves [24576,32768): Wt0[n][k^swz(n)]  n<128, k<64
//      Pre-swizzling the SOURCE lets edge staging be a linear global_load_lds
//      DMA (wave-uniform dest + lane*16) while reads keep the ^swz bank fix
//      (both-sides-or-neither rule for gload_lds swizzles).
// b0,b1,b2: fp32
#define WS_XH  0ull
#define WS_WC  (WS_XH + (size_t)N_NODES * 64 * 2)   // 6,400,000 (1KB-aligned)
#define WS_B0  (WS_WC + 65536)
#define WS_B1  (WS_B0 + 512)
#define WS_B2  (WS_B1 + 512)

#define HC_STRIDE 40            // 32 + 8 fp16 pad; stride must stay ≡0 mod 8 halves
                                // (16B-aligned ds_read_b128); conflict-free write
                                // strides (≡4 mod 8) would misalign the readback.
#define XCONV_BLOCKS 782        // ceil(50000*64 / (512*8))
#define PREP_BLOCKS (XCONV_BLOCKS + 65)

__device__ __forceinline__ float leaky(float t) { return t >= 0.f ? t : SLOPE * t; }

// async 16B/lane global->LDS DMA; LDS dest = wave-uniform base + lane*16
__device__ __forceinline__ void load_lds16(const void* g, void* l) {
    __builtin_amdgcn_global_load_lds(
        (const __attribute__((address_space(1))) void*)g,
        (__attribute__((address_space(3))) void*)l, 16, 0, 0);
}

// ---------------- kernel 1: x->fp16 convert + pre-swizzled weight pack ----------------
__global__ void prep_kernel(const float* __restrict__ x,
                            const float* __restrict__ W0, const float* __restrict__ W1,
                            const float* __restrict__ W2, const float* __restrict__ b0,
                            const float* __restrict__ b1, const float* __restrict__ b2,
                            unsigned char* __restrict__ ws) {
    const int b = blockIdx.x;
    if (b < XCONV_BLOCKS) {                     // x [50000][64] fp32 -> xh fp16
        _Float16* xh = (_Float16*)(ws + WS_XH);
        const int i = (b * 512 + threadIdx.x) * 8;
        if (i < N_NODES * 64) {
            floatx4 u0 = *(const floatx4*)(x + i);
            floatx4 u1 = *(const floatx4*)(x + i + 4);
            half8 h;
            #pragma unroll
            for (int j = 0; j < 4; ++j) { h[j] = (_Float16)u0[j]; h[4 + j] = (_Float16)u1[j]; }
            *(half8*)(xh + i) = h;
        }
        return;
    }
    const int t = (b - XCONV_BLOCKS) * 512 + threadIdx.x;
    _Float16* wc = (_Float16*)(ws + WS_WC);
    if (t < 16384) {                            // W1 [k][n] -> wc[n*128 + (k^swz)]
        int k = t >> 7, n = t & 127;
        wc[n * 128 + (k ^ ((n & 7) << 3))] = (_Float16)W1[k * 128 + n];
    } else if (t < 24576) {                     // W2 [k][n] -> wc[16384 + n*128 + (k^swz)]
        int i2 = t - 16384, k = i2 >> 6, n = i2 & 63;
        wc[16384 + n * 128 + (k ^ ((n & 7) << 3))] = (_Float16)W2[k * 64 + n];
    } else if (t < 32768) {                     // W0 [k][n] -> wc[24576 + n*64 + (k^swz)]
        int i2 = t - 24576, n = i2 >> 6, k = i2 & 63;
        wc[24576 + n * 64 + (k ^ ((n & 7) << 3))] = (_Float16)W0[k * 128 + n];
    } else if (t < 33088) {
        int i2 = t - 32768;
        if (i2 < 128) ((float*)(ws + WS_B0))[i2] = b0[i2];
        else if (i2 < 256) ((float*)(ws + WS_B1))[i2 - 128] = b1[i2 - 128];
        else ((float*)(ws + WS_B2))[i2 - 256] = b2[i2 - 256];
    }
}

// ---------------- kernel 2: per-edge fused 3-layer MLP (round-2 structure) ----------------
// 3125 blocks x 256 edges, self-balancing. 8 waves; each wave owns 32 edges (two
// 16-edge A-frag groups sharing every weight-fragment LDS read). Gathers issue at
// the top; weight staging is ASYNC global_load_lds DMA overlapping the gathers.
__global__ __launch_bounds__(512, 4) void edge_kernel(const int* __restrict__ ei,
                                                      const unsigned char* __restrict__ ws,
                                                      float* __restrict__ out) {
    __shared__ __align__(16) _Float16 wlds[32768];            // 65536 B: w1|w2|w0 swizzled
    __shared__ __align__(16) _Float16 hc[8][16 * HC_STRIDE];  // 10240 B (per-wave)
    __shared__ __align__(16) float b0s[128], b1s[128], b2s[64];
    // total 77056 B -> 2 blocks/CU (16 waves/CU)

    const _Float16* __restrict__ xh = (const _Float16*)(ws + WS_XH);
    const _Float16* __restrict__ w1s = wlds;
    const _Float16* __restrict__ w2s = wlds + 16384;
    const _Float16* __restrict__ w0s = wlds + 24576;

    const int wave = threadIdx.x >> 6, lane = threadIdx.x & 63;
    const int cl = lane & 15, q = lane >> 4;
    const int base = blockIdx.x * 256 + wave * 32;

    // ---- edge indices + gathers issued FIRST: HBM/L3 latency hides under the DMA
    const int r0 = base + cl;
    const int s0 = ei[r0], d0 = ei[N_EDGES + r0];
    const int s1 = ei[r0 + 16], d1 = ei[N_EDGES + r0 + 16];

    const _Float16* ps0 = xh + (size_t)s0 * 64 + q * 8;
    const _Float16* pd0 = xh + (size_t)d0 * 64 + q * 8;
    const _Float16* ps1 = xh + (size_t)s1 * 64 + q * 8;
    const _Float16* pd1 = xh + (size_t)d1 * 64 + q * 8;
    half8 us00 = *(const half8*)(ps0);  half8 us01 = *(const half8*)(ps0 + 32);
    half8 ud00 = *(const half8*)(pd0);  half8 ud01 = *(const half8*)(pd0 + 32);
    half8 us10 = *(const half8*)(ps1);  half8 us11 = *(const half8*)(ps1 + 32);
    half8 ud10 = *(const half8*)(pd1);  half8 ud11 = *(const half8*)(pd1 + 32);

    {   // ---- async weight staging: 64 x 1KB chunks, 8 per wave, zero VGPR traffic.
        // Source is pre-swizzled so linear DMA yields the swizzled LDS image.
        const char* wcg = (const char*)(ws + WS_WC);
        #pragma unroll
        for (int it = 0; it < 8; ++it) {
            const int c = wave * 8 + it;
            load_lds16(wcg + c * 1024 + lane * 16, (char*)wlds + c * 1024);
        }
        const int t = threadIdx.x;
        if (t < 128) { b0s[t] = *(const float*)(ws + WS_B0 + t * 4);
                       b1s[t] = *(const float*)(ws + WS_B1 + t * 4); }
        else if (t < 192) b2s[t - 128] = *(const float*)(ws + WS_B2 + (size_t)(t - 128) * 4);
    }
    __syncthreads();   // drains gathers + DMA (vmcnt 0) + bias writes

    // e = xh[s] + xh[d] (fp16) directly as A-frags: A[m=cl edge][k = ks*32 + q*8 + j]
    half8 a0[2][2];
    a0[0][0] = us00 + ud00;  a0[0][1] = us01 + ud01;
    a0[1][0] = us10 + ud10;  a0[1][1] = us11 + ud11;

    const int swz = (cl & 7) << 3;
    _Float16* hw = &hc[wave][0];

    // ---- layer 0: h0 chunks n=2kk,2kk+1 -> hc round trip -> a1[g][kk] A-frags
    half8 a1[2][4];
    #pragma unroll
    for (int kk = 0; kk < 4; ++kk) {
        const int nA = 2 * kk, nB = 2 * kk + 1;
        half8 wA0 = *(const half8*)&w0s[((nA * 16 + cl) * 64 + q * 8) ^ swz];
        half8 wA1 = *(const half8*)&w0s[((nA * 16 + cl) * 64 + 32 + q * 8) ^ swz];
        half8 wB0 = *(const half8*)&w0s[((nB * 16 + cl) * 64 + q * 8) ^ swz];
        half8 wB1 = *(const half8*)&w0s[((nB * 16 + cl) * 64 + 32 + q * 8) ^ swz];
        const float bbA = b0s[nA * 16 + cl], bbB = b0s[nB * 16 + cl];
        #pragma unroll
        for (int g = 0; g < 2; ++g) {       // sequential hc reuse (per-wave, lgkm-ordered)
            floatx4 cA = {0.f, 0.f, 0.f, 0.f}, cB = {0.f, 0.f, 0.f, 0.f};
            cA = __builtin_amdgcn_mfma_f32_16x16x32_f16(a0[g][0], wA0, cA, 0, 0, 0);
            cA = __builtin_amdgcn_mfma_f32_16x16x32_f16(a0[g][1], wA1, cA, 0, 0, 0);
            cB = __builtin_amdgcn_mfma_f32_16x16x32_f16(a0[g][0], wB0, cB, 0, 0, 0);
            cB = __builtin_amdgcn_mfma_f32_16x16x32_f16(a0[g][1], wB1, cB, 0, 0, 0);
            #pragma unroll
            for (int rr = 0; rr < 4; ++rr) {   // C/D: row(edge)=q*4+rr, col=cl
                hw[(q * 4 + rr) * HC_STRIDE + cl]      = (_Float16)leaky(cA[rr] + bbA);
                hw[(q * 4 + rr) * HC_STRIDE + 16 + cl] = (_Float16)leaky(cB[rr] + bbB);
            }
            a1[g][kk] = *(const half8*)&hw[cl * HC_STRIDE + q * 8];
        }
    }

    // ---- layers 1+2, interleaved by 32-col k-chunks; weight frags shared by both groups
    floatx4 acc2[2][4];
    #pragma unroll
    for (int g = 0; g < 2; ++g)
        #pragma unroll
        for (int n2 = 0; n2 < 4; ++n2) acc2[g][n2] = (floatx4){0.f, 0.f, 0.f, 0.f};

    #pragma unroll
    for (int ks = 0; ks < 4; ++ks) {
        const int nA = 2 * ks, nB = 2 * ks + 1;
        floatx4 cA0 = {0.f,0.f,0.f,0.f}, cA1 = {0.f,0.f,0.f,0.f};
        floatx4 cB0 = {0.f,0.f,0.f,0.f}, cB1 = {0.f,0.f,0.f,0.f};
        #pragma unroll
        for (int kk = 0; kk < 4; ++kk) {
            half8 b = *(const half8*)&w1s[((nA * 16 + cl) * 128 + kk * 32 + q * 8) ^ swz];
            cA0 = __builtin_amdgcn_mfma_f32_16x16x32_f16(a1[0][kk], b, cA0, 0, 0, 0);
            cA1 = __builtin_amdgcn_mfma_f32_16x16x32_f16(a1[1][kk], b, cA1, 0, 0, 0);
        }
        #pragma unroll
        for (int kk = 0; kk < 4; ++kk) {
            half8 b = *(const half8*)&w1s[((nB * 16 + cl) * 128 + kk * 32 + q * 8) ^ swz];
            cB0 = __builtin_amdgcn_mfma_f32_16x16x32_f16(a1[0][kk], b, cB0, 0, 0, 0);
            cB1 = __builtin_amdgcn_mfma_f32_16x16x32_f16(a1[1][kk], b, cB1, 0, 0, 0);
        }
        const float bbA = b1s[nA * 16 + cl], bbB = b1s[nB * 16 + cl];
        half8 a2[2];
        #pragma unroll
        for (int g = 0; g < 2; ++g) {       // sequential hc reuse again
            const floatx4 cc0 = g ? cA1 : cA0;
            const floatx4 cc1 = g ? cB1 : cB0;
            #pragma unroll
            for (int rr = 0; rr < 4; ++rr) {
                hw[(q * 4 + rr) * HC_STRIDE + cl]      = (_Float16)leaky(cc0[rr] + bbA);
                hw[(q * 4 + rr) * HC_STRIDE + 16 + cl] = (_Float16)leaky(cc1[rr] + bbB);
            }
            a2[g] = *(const half8*)&hw[cl * HC_STRIDE + q * 8];
        }
        #pragma unroll
        for (int n2 = 0; n2 < 4; ++n2) {
            half8 b = *(const half8*)&w2s[((n2 * 16 + cl) * 128 + ks * 32 + q * 8) ^ swz];
            // swapped operands: lane holds 4 CONSECUTIVE output features for edge cl
            acc2[0][n2] = __builtin_amdgcn_mfma_f32_16x16x32_f16(b, a2[0], acc2[0][n2], 0, 0, 0);
            acc2[1][n2] = __builtin_amdgcn_mfma_f32_16x16x32_f16(b, a2[1], acc2[1][n2], 0, 0, 0);
        }
    }

    // epilogue: register-direct float4 stores (normal stores; NT measured 1.88x write amp)
    #pragma unroll
    for (int n2 = 0; n2 < 4; ++n2) {
        floatx4 bb = *(const floatx4*)&b2s[n2 * 16 + q * 4];
        #pragma unroll
        for (int g = 0; g < 2; ++g) {
            floatx4 o;
            #pragma unroll
            for (int rr = 0; rr < 4; ++rr) o[rr] = leaky(acc2[g][n2][rr] + bb[rr]);
            *(floatx4*)(out + (size_t)(base + g * 16 + cl) * 64 + n2 * 16 + q * 4) = o;
        }
    }
}

extern "C" void kernel_launch(void* const* d_in, const int* in_sizes, int n_in,
                              void* d_out, int out_size, void* d_ws, size_t ws_size,
                              hipStream_t stream) {
    const float* x  = (const float*)d_in[0];
    const int*   ei = (const int*)d_in[1];     // int inputs arrive as int32
    const float* W0 = (const float*)d_in[2];
    const float* b0 = (const float*)d_in[3];
    const float* W1 = (const float*)d_in[4];
    const float* b1 = (const float*)d_in[5];
    const float* W2 = (const float*)d_in[6];
    const float* b2 = (const float*)d_in[7];
    float* out = (float*)d_out;
    unsigned char* ws = (unsigned char*)d_ws;

    prep_kernel<<<PREP_BLOCKS, 512, 0, stream>>>(x, W0, W1, W2, b0, b1, b2, ws);
    edge_kernel<<<N_EDGES / 256, 512, 0, stream>>>(ei, ws, out);
}

// Round 7
// 277.373 us; speedup vs baseline: 1.2066x; 1.0327x over previous
//
#include <hip/hip_runtime.h>

typedef _Float16 half8  __attribute__((ext_vector_type(8)));
typedef float    floatx4 __attribute__((ext_vector_type(4)));

#define N_NODES 50000
#define N_EDGES 800000
#define SLOPE 0.05f

// ---- workspace layout (bytes) ----
// xh:  fp16 [N_NODES][64] = fp16(x)        (gather table: 128 B/row, 6.4 MB)
// wc:  fp16 [32768]  PRE-SWIZZLED weight block, laid out exactly as the edge
//      kernel's unified LDS image (64 KB):
//        halves [    0,16384): Wt1[n][k^swz(n)]  n<128, k<128  (swz(n)=(n&7)<<3)
//        halves [16384,24576): Wt2[n][k^swz(n)]  n<64,  k<128
//        halves [24576,32768): Wt0[n][k^swz(n)]  n<128, k<64
//      Pre-swizzling the SOURCE makes edge-kernel staging a pure linear copy
//      while reads keep the ^swz bank fix.
// b0,b1,b2: fp32
#define WS_XH  0ull
#define WS_WC  (WS_XH + (size_t)N_NODES * 64 * 2)   // 6,400,000 (16B-aligned)
#define WS_B0  (WS_WC + 65536)
#define WS_B1  (WS_B0 + 512)
#define WS_B2  (WS_B1 + 512)

#define HC_STRIDE 40            // 32 + 8 fp16 pad; stride must stay ≡0 mod 8 halves
                                // (16B-aligned ds_read_b128)
#define XCONV_BLOCKS 782        // ceil(50000*64 / (512*8))
#define PREP_BLOCKS (XCONV_BLOCKS + 65)

__device__ __forceinline__ float leaky(float t) { return t >= 0.f ? t : SLOPE * t; }

// ---------------- kernel 1: x->fp16 convert + pre-swizzled weight pack ----------------
__global__ void prep_kernel(const float* __restrict__ x,
                            const float* __restrict__ W0, const float* __restrict__ W1,
                            const float* __restrict__ W2, const float* __restrict__ b0,
                            const float* __restrict__ b1, const float* __restrict__ b2,
                            unsigned char* __restrict__ ws) {
    const int b = blockIdx.x;
    if (b < XCONV_BLOCKS) {                     // x [50000][64] fp32 -> xh fp16
        _Float16* xh = (_Float16*)(ws + WS_XH);
        const int i = (b * 512 + threadIdx.x) * 8;
        if (i < N_NODES * 64) {
            floatx4 u0 = *(const floatx4*)(x + i);
            floatx4 u1 = *(const floatx4*)(x + i + 4);
            half8 h;
            #pragma unroll
            for (int j = 0; j < 4; ++j) { h[j] = (_Float16)u0[j]; h[4 + j] = (_Float16)u1[j]; }
            *(half8*)(xh + i) = h;
        }
        return;
    }
    const int t = (b - XCONV_BLOCKS) * 512 + threadIdx.x;
    _Float16* wc = (_Float16*)(ws + WS_WC);
    if (t < 16384) {                            // W1 [k][n] -> wc[n*128 + (k^swz)]
        int k = t >> 7, n = t & 127;
        wc[n * 128 + (k ^ ((n & 7) << 3))] = (_Float16)W1[k * 128 + n];
    } else if (t < 24576) {                     // W2 [k][n] -> wc[16384 + n*128 + (k^swz)]
        int i2 = t - 16384, k = i2 >> 6, n = i2 & 63;
        wc[16384 + n * 128 + (k ^ ((n & 7) << 3))] = (_Float16)W2[k * 64 + n];
    } else if (t < 32768) {                     // W0 [k][n] -> wc[24576 + n*64 + (k^swz)]
        int i2 = t - 24576, n = i2 >> 6, k = i2 & 63;
        wc[24576 + n * 64 + (k ^ ((n & 7) << 3))] = (_Float16)W0[k * 128 + n];
    } else if (t < 33088) {
        int i2 = t - 32768;
        if (i2 < 128) ((float*)(ws + WS_B0))[i2] = b0[i2];
        else if (i2 < 256) ((float*)(ws + WS_B1))[i2 - 128] = b1[i2 - 128];
        else ((float*)(ws + WS_B2))[i2 - 256] = b2[i2 - 256];
    }
}

// ---------------- kernel 2: per-edge fused 3-layer MLP (round-2 structure) ----------------
// 3125 blocks x 256 edges, self-balancing. 8 waves; each wave owns 32 edges (two
// 16-edge A-frag groups sharing every weight-fragment LDS read).
//
// hc exchange swizzle: physical col = logical col ^ ((row&8)<<1).
//  - writes (b16, row=q*4+rr): q∈{0,2} / q∈{1,3} previously hit identical bank
//    octets (4-way, measured 6.4M conflict-cycles); the XOR moves q=2,3 to
//    disjoint octets -> 2 lanes/bank (free per m136).
//  - reads (b128, row=cl): XOR by 16 halves maps an aligned 8-half block to
//    another aligned block -> contiguity + 16B alignment preserved.
__global__ __launch_bounds__(512, 4) void edge_kernel(const int* __restrict__ ei,
                                                      const unsigned char* __restrict__ ws,
                                                      float* __restrict__ out) {
    __shared__ __align__(16) _Float16 wlds[32768];            // 65536 B: w1|w2|w0 swizzled
    __shared__ __align__(16) _Float16 hc[8][16 * HC_STRIDE];  // 10240 B (per-wave)
    __shared__ __align__(16) float b0s[128], b1s[128], b2s[64];
    // total 77056 B -> 2 blocks/CU (16 waves/CU)

    const _Float16* __restrict__ xh = (const _Float16*)(ws + WS_XH);
    const _Float16* __restrict__ w1s = wlds;
    const _Float16* __restrict__ w2s = wlds + 16384;
    const _Float16* __restrict__ w0s = wlds + 24576;

    const int wave = threadIdx.x >> 6, lane = threadIdx.x & 63;
    const int cl = lane & 15, q = lane >> 4;
    const int base = blockIdx.x * 256 + wave * 32;

    // ---- edge indices + gathers issued FIRST: latency hides under weight staging
    const int r0 = base + cl;
    const int s0 = ei[r0], d0 = ei[N_EDGES + r0];
    const int s1 = ei[r0 + 16], d1 = ei[N_EDGES + r0 + 16];

    const _Float16* ps0 = xh + (size_t)s0 * 64 + q * 8;
    const _Float16* pd0 = xh + (size_t)d0 * 64 + q * 8;
    const _Float16* ps1 = xh + (size_t)s1 * 64 + q * 8;
    const _Float16* pd1 = xh + (size_t)d1 * 64 + q * 8;
    half8 us00 = *(const half8*)(ps0);  half8 us01 = *(const half8*)(ps0 + 32);
    half8 ud00 = *(const half8*)(pd0);  half8 ud01 = *(const half8*)(pd0 + 32);
    half8 us10 = *(const half8*)(ps1);  half8 us11 = *(const half8*)(ps1 + 32);
    half8 ud10 = *(const half8*)(pd1);  half8 ud11 = *(const half8*)(pd1 + 32);

    {   // ---- weight staging: pure linear 64KB copy (source pre-swizzled by prep)
        const half8* __restrict__ wcg = (const half8*)(ws + WS_WC);
        half8* wl = (half8*)wlds;
        #pragma unroll
        for (int it = 0; it < 8; ++it) {
            const int c = threadIdx.x + it * 512;   // 4096 chunks of 16B
            wl[c] = wcg[c];
        }
        const int t = threadIdx.x;
        if (t < 128) { b0s[t] = *(const float*)(ws + WS_B0 + t * 4);
                       b1s[t] = *(const float*)(ws + WS_B1 + t * 4); }
        else if (t < 192) b2s[t - 128] = *(const float*)(ws + WS_B2 + (size_t)(t - 128) * 4);
    }
    __syncthreads();

    // e = xh[s] + xh[d] (fp16) directly as A-frags: A[m=cl edge][k = ks*32 + q*8 + j]
    half8 a0[2][2];
    a0[0][0] = us00 + ud00;  a0[0][1] = us01 + ud01;
    a0[1][0] = us10 + ud10;  a0[1][1] = us11 + ud11;

    const int swz = (cl & 7) << 3;                 // weight-tile bank swizzle
    const int wxor = (q & 2) << 3;                 // hc write-side XOR ((row&8)<<1)
    _Float16* hw = &hc[wave][0];
    // hc read address: logical [row=cl][k=q*8..] with matching XOR keyed by cl
    const int hrd = cl * HC_STRIDE + ((q * 8) ^ ((cl & 8) << 1));

    // ---- layer 0: h0 chunks n=2kk,2kk+1 -> hc round trip -> a1[g][kk] A-frags
    half8 a1[2][4];
    #pragma unroll
    for (int kk = 0; kk < 4; ++kk) {
        const int nA = 2 * kk, nB = 2 * kk + 1;
        half8 wA0 = *(const half8*)&w0s[((nA * 16 + cl) * 64 + q * 8) ^ swz];
        half8 wA1 = *(const half8*)&w0s[((nA * 16 + cl) * 64 + 32 + q * 8) ^ swz];
        half8 wB0 = *(const half8*)&w0s[((nB * 16 + cl) * 64 + q * 8) ^ swz];
        half8 wB1 = *(const half8*)&w0s[((nB * 16 + cl) * 64 + 32 + q * 8) ^ swz];
        const float bbA = b0s[nA * 16 + cl], bbB = b0s[nB * 16 + cl];
        #pragma unroll
        for (int g = 0; g < 2; ++g) {       // sequential hc reuse (per-wave, lgkm-ordered)
            floatx4 cA = {bbA, bbA, bbA, bbA};   // bias folded into accumulator init
            floatx4 cB = {bbB, bbB, bbB, bbB};
            __builtin_amdgcn_s_setprio(1);
            cA = __builtin_amdgcn_mfma_f32_16x16x32_f16(a0[g][0], wA0, cA, 0, 0, 0);
            cA = __builtin_amdgcn_mfma_f32_16x16x32_f16(a0[g][1], wA1, cA, 0, 0, 0);
            cB = __builtin_amdgcn_mfma_f32_16x16x32_f16(a0[g][0], wB0, cB, 0, 0, 0);
            cB = __builtin_amdgcn_mfma_f32_16x16x32_f16(a0[g][1], wB1, cB, 0, 0, 0);
            __builtin_amdgcn_s_setprio(0);
            #pragma unroll
            for (int rr = 0; rr < 4; ++rr) {   // C/D: row(edge)=q*4+rr, col=cl
                hw[(q * 4 + rr) * HC_STRIDE + (cl ^ wxor)]        = (_Float16)leaky(cA[rr]);
                hw[(q * 4 + rr) * HC_STRIDE + ((16 + cl) ^ wxor)] = (_Float16)leaky(cB[rr]);
            }
            a1[g][kk] = *(const half8*)&hw[hrd];
        }
    }

    // ---- layers 1+2, interleaved by 32-col k-chunks; weight frags shared by both groups
    floatx4 acc2[2][4];
    #pragma unroll
    for (int n2 = 0; n2 < 4; ++n2) {
        const floatx4 bb2 = *(const floatx4*)&b2s[n2 * 16 + q * 4];  // bias folded
        acc2[0][n2] = bb2;  acc2[1][n2] = bb2;
    }

    #pragma unroll
    for (int ks = 0; ks < 4; ++ks) {
        const int nA = 2 * ks, nB = 2 * ks + 1;
        const float bbA = b1s[nA * 16 + cl], bbB = b1s[nB * 16 + cl];
        floatx4 cA0 = {bbA,bbA,bbA,bbA}, cA1 = {bbA,bbA,bbA,bbA};
        floatx4 cB0 = {bbB,bbB,bbB,bbB}, cB1 = {bbB,bbB,bbB,bbB};
        __builtin_amdgcn_s_setprio(1);
        #pragma unroll
        for (int kk = 0; kk < 4; ++kk) {
            half8 b = *(const half8*)&w1s[((nA * 16 + cl) * 128 + kk * 32 + q * 8) ^ swz];
            cA0 = __builtin_amdgcn_mfma_f32_16x16x32_f16(a1[0][kk], b, cA0, 0, 0, 0);
            cA1 = __builtin_amdgcn_mfma_f32_16x16x32_f16(a1[1][kk], b, cA1, 0, 0, 0);
        }
        #pragma unroll
        for (int kk = 0; kk < 4; ++kk) {
            half8 b = *(const half8*)&w1s[((nB * 16 + cl) * 128 + kk * 32 + q * 8) ^ swz];
            cB0 = __builtin_amdgcn_mfma_f32_16x16x32_f16(a1[0][kk], b, cB0, 0, 0, 0);
            cB1 = __builtin_amdgcn_mfma_f32_16x16x32_f16(a1[1][kk], b, cB1, 0, 0, 0);
        }
        __builtin_amdgcn_s_setprio(0);
        half8 a2[2];
        #pragma unroll
        for (int g = 0; g < 2; ++g) {       // sequential hc reuse again
            const floatx4 cc0 = g ? cA1 : cA0;
            const floatx4 cc1 = g ? cB1 : cB0;
            #pragma unroll
            for (int rr = 0; rr < 4; ++rr) {
                hw[(q * 4 + rr) * HC_STRIDE + (cl ^ wxor)]        = (_Float16)leaky(cc0[rr]);
                hw[(q * 4 + rr) * HC_STRIDE + ((16 + cl) ^ wxor)] = (_Float16)leaky(cc1[rr]);
            }
            a2[g] = *(const half8*)&hw[hrd];
        }
        __builtin_amdgcn_s_setprio(1);
        #pragma unroll
        for (int n2 = 0; n2 < 4; ++n2) {
            half8 b = *(const half8*)&w2s[((n2 * 16 + cl) * 128 + ks * 32 + q * 8) ^ swz];
            // swapped operands: lane holds 4 CONSECUTIVE output features for edge cl
            acc2[0][n2] = __builtin_amdgcn_mfma_f32_16x16x32_f16(b, a2[0], acc2[0][n2], 0, 0, 0);
            acc2[1][n2] = __builtin_amdgcn_mfma_f32_16x16x32_f16(b, a2[1], acc2[1][n2], 0, 0, 0);
        }
        __builtin_amdgcn_s_setprio(0);
    }

    // epilogue: register-direct float4 stores; g-outer so each 16-row group's four
    // 64B sectors complete in 4 consecutive instructions (full-line assembly)
    #pragma unroll
    for (int g = 0; g < 2; ++g) {
        #pragma unroll
        for (int n2 = 0; n2 < 4; ++n2) {
            floatx4 o;
            #pragma unroll
            for (int rr = 0; rr < 4; ++rr) o[rr] = leaky(acc2[g][n2][rr]);
            *(floatx4*)(out + (size_t)(base + g * 16 + cl) * 64 + n2 * 16 + q * 4) = o;
        }
    }
}

extern "C" void kernel_launch(void* const* d_in, const int* in_sizes, int n_in,
                              void* d_out, int out_size, void* d_ws, size_t ws_size,
                              hipStream_t stream) {
    const float* x  = (const float*)d_in[0];
    const int*   ei = (const int*)d_in[1];     // int inputs arrive as int32
    const float* W0 = (const float*)d_in[2];
    const float* b0 = (const float*)d_in[3];
    const float* W1 = (const float*)d_in[4];
    const float* b1 = (const float*)d_in[5];
    const float* W2 = (const float*)d_in[6];
    const float* b2 = (const float*)d_in[7];
    float* out = (float*)d_out;
    unsigned char* ws = (unsigned char*)d_ws;

    prep_kernel<<<PREP_BLOCKS, 512, 0, stream>>>(x, W0, W1, W2, b0, b1, b2, ws);
    edge_kernel<<<N_EDGES / 256, 512, 0, stream>>>(ei, ws, out);
}

// Round 8
// 276.594 us; speedup vs baseline: 1.2100x; 1.0028x over previous
//
#include <hip/hip_runtime.h>

typedef _Float16 half8  __attribute__((ext_vector_type(8)));
typedef float    floatx4 __attribute__((ext_vector_type(4)));

#define N_NODES 50000
#define N_EDGES 800000
#define SLOPE 0.05f

// ---- workspace layout (bytes) ----
// xh:  fp16 [N_NODES][64] = fp16(x)        (gather table: 128 B/row, 6.4 MB)
// wc:  fp16 [32768]  PRE-SWIZZLED weight block, laid out exactly as the edge
//      kernel's unified LDS image (64 KB):
//        halves [    0,16384): Wt1[n][k^swz(n)]  n<128, k<128  (swz(n)=(n&7)<<3)
//        halves [16384,24576): Wt2[n][k^swz(n)]  n<64,  k<128
//        halves [24576,32768): Wt0[n][k^swz(n)]  n<128, k<64
// b0,b1,b2: fp32
#define WS_XH  0ull
#define WS_WC  (WS_XH + (size_t)N_NODES * 64 * 2)   // 6,400,000 (16B-aligned)
#define WS_B0  (WS_WC + 65536)
#define WS_B1  (WS_B0 + 512)
#define WS_B2  (WS_B1 + 512)

#define HC_STRIDE 40            // 32 + 8 fp16 pad; ≡0 mod 8 halves (b128-aligned)
#define XCONV_BLOCKS 782        // ceil(50000*64 / (512*8))
#define PREP_BLOCKS (XCONV_BLOCKS + 65)

__device__ __forceinline__ float leaky(float t) { return t >= 0.f ? t : SLOPE * t; }

// ---------------- kernel 1: x->fp16 convert + pre-swizzled weight pack ----------------
__global__ void prep_kernel(const float* __restrict__ x,
                            const float* __restrict__ W0, const float* __restrict__ W1,
                            const float* __restrict__ W2, const float* __restrict__ b0,
                            const float* __restrict__ b1, const float* __restrict__ b2,
                            unsigned char* __restrict__ ws) {
    const int b = blockIdx.x;
    if (b < XCONV_BLOCKS) {                     // x [50000][64] fp32 -> xh fp16
        _Float16* xh = (_Float16*)(ws + WS_XH);
        const int i = (b * 512 + threadIdx.x) * 8;
        if (i < N_NODES * 64) {
            floatx4 u0 = *(const floatx4*)(x + i);
            floatx4 u1 = *(const floatx4*)(x + i + 4);
            half8 h;
            #pragma unroll
            for (int j = 0; j < 4; ++j) { h[j] = (_Float16)u0[j]; h[4 + j] = (_Float16)u1[j]; }
            *(half8*)(xh + i) = h;
        }
        return;
    }
    const int t = (b - XCONV_BLOCKS) * 512 + threadIdx.x;
    _Float16* wc = (_Float16*)(ws + WS_WC);
    if (t < 16384) {                            // W1 [k][n] -> wc[n*128 + (k^swz)]
        int k = t >> 7, n = t & 127;
        wc[n * 128 + (k ^ ((n & 7) << 3))] = (_Float16)W1[k * 128 + n];
    } else if (t < 24576) {                     // W2 [k][n] -> wc[16384 + n*128 + (k^swz)]
        int i2 = t - 16384, k = i2 >> 6, n = i2 & 63;
        wc[16384 + n * 128 + (k ^ ((n & 7) << 3))] = (_Float16)W2[k * 64 + n];
    } else if (t < 32768) {                     // W0 [k][n] -> wc[24576 + n*64 + (k^swz)]
        int i2 = t - 24576, n = i2 >> 6, k = i2 & 63;
        wc[24576 + n * 64 + (k ^ ((n & 7) << 3))] = (_Float16)W0[k * 128 + n];
    } else if (t < 33088) {
        int i2 = t - 32768;
        if (i2 < 128) ((float*)(ws + WS_B0))[i2] = b0[i2];
        else if (i2 < 256) ((float*)(ws + WS_B1))[i2 - 128] = b1[i2 - 128];
        else ((float*)(ws + WS_B2))[i2 - 256] = b2[i2 - 256];
    }
}

// ---------------- kernel 2: per-edge fused 3-layer MLP ----------------
// 3125 blocks x 256 edges. 8 waves; each wave owns 32 edges (two 16-edge A-frag
// groups sharing every weight-fragment LDS read).
// EPILOGUE (new): R3 counters showed the scattered 64B-sector store pattern cost
// 428MB WRITE (2.09x ideal) + ~144MB RFO FETCH, while the harness's contiguous
// fill writes 1.00x. So: stage out-tile through wlds (weights dead by then) and
// emit fully-contiguous 1KB-per-instruction NONTEMPORAL wave stores.
__global__ __launch_bounds__(512, 4) void edge_kernel(const int* __restrict__ ei,
                                                      const unsigned char* __restrict__ ws,
                                                      float* __restrict__ out) {
    __shared__ __align__(16) _Float16 wlds[32768];            // 65536 B: w1|w2|w0 swizzled
    __shared__ __align__(16) _Float16 hc[8][16 * HC_STRIDE];  // 10240 B (per-wave)
    __shared__ __align__(16) float b0s[128], b1s[128], b2s[64];
    // total 77056 B -> 2 blocks/CU (16 waves/CU)

    const _Float16* __restrict__ xh = (const _Float16*)(ws + WS_XH);
    const _Float16* __restrict__ w1s = wlds;
    const _Float16* __restrict__ w2s = wlds + 16384;
    const _Float16* __restrict__ w0s = wlds + 24576;

    const int wave = threadIdx.x >> 6, lane = threadIdx.x & 63;
    const int cl = lane & 15, q = lane >> 4;
    const int base = blockIdx.x * 256 + wave * 32;

    // ---- edge indices + gathers issued FIRST: latency hides under weight staging
    const int r0 = base + cl;
    const int s0 = ei[r0], d0 = ei[N_EDGES + r0];
    const int s1 = ei[r0 + 16], d1 = ei[N_EDGES + r0 + 16];

    const _Float16* ps0 = xh + (size_t)s0 * 64 + q * 8;
    const _Float16* pd0 = xh + (size_t)d0 * 64 + q * 8;
    const _Float16* ps1 = xh + (size_t)s1 * 64 + q * 8;
    const _Float16* pd1 = xh + (size_t)d1 * 64 + q * 8;
    half8 us00 = *(const half8*)(ps0);  half8 us01 = *(const half8*)(ps0 + 32);
    half8 ud00 = *(const half8*)(pd0);  half8 ud01 = *(const half8*)(pd0 + 32);
    half8 us10 = *(const half8*)(ps1);  half8 us11 = *(const half8*)(ps1 + 32);
    half8 ud10 = *(const half8*)(pd1);  half8 ud11 = *(const half8*)(pd1 + 32);

    {   // ---- weight staging: pure linear 64KB copy (source pre-swizzled by prep)
        const half8* __restrict__ wcg = (const half8*)(ws + WS_WC);
        half8* wl = (half8*)wlds;
        #pragma unroll
        for (int it = 0; it < 8; ++it) {
            const int c = threadIdx.x + it * 512;   // 4096 chunks of 16B
            wl[c] = wcg[c];
        }
        const int t = threadIdx.x;
        if (t < 128) { b0s[t] = *(const float*)(ws + WS_B0 + t * 4);
                       b1s[t] = *(const float*)(ws + WS_B1 + t * 4); }
        else if (t < 192) b2s[t - 128] = *(const float*)(ws + WS_B2 + (size_t)(t - 128) * 4);
    }
    __syncthreads();

    // e = xh[s] + xh[d] (fp16) directly as A-frags: A[m=cl edge][k = ks*32 + q*8 + j]
    half8 a0[2][2];
    a0[0][0] = us00 + ud00;  a0[0][1] = us01 + ud01;
    a0[1][0] = us10 + ud10;  a0[1][1] = us11 + ud11;

    const int swz = (cl & 7) << 3;                 // weight-tile bank swizzle
    const int wxor = (q & 2) << 3;                 // hc write-side XOR ((row&8)<<1)
    _Float16* hw = &hc[wave][0];
    const int hrd = cl * HC_STRIDE + ((q * 8) ^ ((cl & 8) << 1));

    // ---- layer 0: h0 chunks n=2kk,2kk+1 -> hc round trip -> a1[g][kk] A-frags
    half8 a1[2][4];
    #pragma unroll
    for (int kk = 0; kk < 4; ++kk) {
        const int nA = 2 * kk, nB = 2 * kk + 1;
        half8 wA0 = *(const half8*)&w0s[((nA * 16 + cl) * 64 + q * 8) ^ swz];
        half8 wA1 = *(const half8*)&w0s[((nA * 16 + cl) * 64 + 32 + q * 8) ^ swz];
        half8 wB0 = *(const half8*)&w0s[((nB * 16 + cl) * 64 + q * 8) ^ swz];
        half8 wB1 = *(const half8*)&w0s[((nB * 16 + cl) * 64 + 32 + q * 8) ^ swz];
        const float bbA = b0s[nA * 16 + cl], bbB = b0s[nB * 16 + cl];
        #pragma unroll
        for (int g = 0; g < 2; ++g) {       // sequential hc reuse (per-wave, lgkm-ordered)
            floatx4 cA = {bbA, bbA, bbA, bbA};   // bias folded into accumulator init
            floatx4 cB = {bbB, bbB, bbB, bbB};
            __builtin_amdgcn_s_setprio(1);
            cA = __builtin_amdgcn_mfma_f32_16x16x32_f16(a0[g][0], wA0, cA, 0, 0, 0);
            cA = __builtin_amdgcn_mfma_f32_16x16x32_f16(a0[g][1], wA1, cA, 0, 0, 0);
            cB = __builtin_amdgcn_mfma_f32_16x16x32_f16(a0[g][0], wB0, cB, 0, 0, 0);
            cB = __builtin_amdgcn_mfma_f32_16x16x32_f16(a0[g][1], wB1, cB, 0, 0, 0);
            __builtin_amdgcn_s_setprio(0);
            #pragma unroll
            for (int rr = 0; rr < 4; ++rr) {   // C/D: row(edge)=q*4+rr, col=cl
                hw[(q * 4 + rr) * HC_STRIDE + (cl ^ wxor)]        = (_Float16)leaky(cA[rr]);
                hw[(q * 4 + rr) * HC_STRIDE + ((16 + cl) ^ wxor)] = (_Float16)leaky(cB[rr]);
            }
            a1[g][kk] = *(const half8*)&hw[hrd];
        }
    }

    // ---- layers 1+2, interleaved by 32-col k-chunks; weight frags shared by both groups
    floatx4 acc2[2][4];
    #pragma unroll
    for (int n2 = 0; n2 < 4; ++n2) {
        const floatx4 bb2 = *(const floatx4*)&b2s[n2 * 16 + q * 4];  // bias folded
        acc2[0][n2] = bb2;  acc2[1][n2] = bb2;
    }

    #pragma unroll
    for (int ks = 0; ks < 4; ++ks) {
        const int nA = 2 * ks, nB = 2 * ks + 1;
        const float bbA = b1s[nA * 16 + cl], bbB = b1s[nB * 16 + cl];
        floatx4 cA0 = {bbA,bbA,bbA,bbA}, cA1 = {bbA,bbA,bbA,bbA};
        floatx4 cB0 = {bbB,bbB,bbB,bbB}, cB1 = {bbB,bbB,bbB,bbB};
        __builtin_amdgcn_s_setprio(1);
        #pragma unroll
        for (int kk = 0; kk < 4; ++kk) {
            half8 b = *(const half8*)&w1s[((nA * 16 + cl) * 128 + kk * 32 + q * 8) ^ swz];
            cA0 = __builtin_amdgcn_mfma_f32_16x16x32_f16(a1[0][kk], b, cA0, 0, 0, 0);
            cA1 = __builtin_amdgcn_mfma_f32_16x16x32_f16(a1[1][kk], b, cA1, 0, 0, 0);
        }
        #pragma unroll
        for (int kk = 0; kk < 4; ++kk) {
            half8 b = *(const half8*)&w1s[((nB * 16 + cl) * 128 + kk * 32 + q * 8) ^ swz];
            cB0 = __builtin_amdgcn_mfma_f32_16x16x32_f16(a1[0][kk], b, cB0, 0, 0, 0);
            cB1 = __builtin_amdgcn_mfma_f32_16x16x32_f16(a1[1][kk], b, cB1, 0, 0, 0);
        }
        __builtin_amdgcn_s_setprio(0);
        half8 a2[2];
        #pragma unroll
        for (int g = 0; g < 2; ++g) {       // sequential hc reuse again
            const floatx4 cc0 = g ? cA1 : cA0;
            const floatx4 cc1 = g ? cB1 : cB0;
            #pragma unroll
            for (int rr = 0; rr < 4; ++rr) {
                hw[(q * 4 + rr) * HC_STRIDE + (cl ^ wxor)]        = (_Float16)leaky(cc0[rr]);
                hw[(q * 4 + rr) * HC_STRIDE + ((16 + cl) ^ wxor)] = (_Float16)leaky(cc1[rr]);
            }
            a2[g] = *(const half8*)&hw[hrd];
        }
        __builtin_amdgcn_s_setprio(1);
        #pragma unroll
        for (int n2 = 0; n2 < 4; ++n2) {
            half8 b = *(const half8*)&w2s[((n2 * 16 + cl) * 128 + ks * 32 + q * 8) ^ swz];
            // swapped operands: lane holds 4 CONSECUTIVE output features for edge cl
            acc2[0][n2] = __builtin_amdgcn_mfma_f32_16x16x32_f16(b, a2[0], acc2[0][n2], 0, 0, 0);
            acc2[1][n2] = __builtin_amdgcn_mfma_f32_16x16x32_f16(b, a2[1], acc2[1][n2], 0, 0, 0);
        }
        __builtin_amdgcn_s_setprio(0);
    }

    // ---- epilogue: stage the block's 64KB out-tile in wlds (weights are dead),
    // then fully-contiguous nontemporal wave stores (1KB/instruction, full lines).
    __syncthreads();               // all weight reads complete; wlds reusable
    {
        float* ob = (float*)wlds + wave * 2048;       // 8KB per-wave region
        #pragma unroll
        for (int g = 0; g < 2; ++g) {
            #pragma unroll
            for (int n2 = 0; n2 < 4; ++n2) {
                const int row = g * 16 + cl;                    // local out row
                const int cph = (n2 * 4 + q) ^ (row & 15);      // f4-col bank spread
                floatx4 o;
                #pragma unroll
                for (int rr = 0; rr < 4; ++rr) o[rr] = leaky(acc2[g][n2][rr]);
                *(floatx4*)&ob[row * 64 + cph * 4] = o;
            }
        }
        // linear readback (inverse of the same XOR) -> contiguous global NT stores
        #pragma unroll
        for (int it = 0; it < 8; ++it) {
            const int f = it * 64 + lane;                       // f4 index in region
            const int row = f >> 4, c = f & 15;
            const int cph = c ^ (row & 15);
            floatx4 v = *(const floatx4*)&ob[row * 64 + cph * 4];
            __builtin_nontemporal_store(v,
                (floatx4*)(out + (size_t)(base + row) * 64 + c * 4));
        }
    }
}

extern "C" void kernel_launch(void* const* d_in, const int* in_sizes, int n_in,
                              void* d_out, int out_size, void* d_ws, size_t ws_size,
                              hipStream_t stream) {
    const float* x  = (const float*)d_in[0];
    const int*   ei = (const int*)d_in[1];     // int inputs arrive as int32
    const float* W0 = (const float*)d_in[2];
    const float* b0 = (const float*)d_in[3];
    const float* W1 = (const float*)d_in[4];
    const float* b1 = (const float*)d_in[5];
    const float* W2 = (const float*)d_in[6];
    const float* b2 = (const float*)d_in[7];
    float* out = (float*)d_out;
    unsigned char* ws = (unsigned char*)d_ws;

    prep_kernel<<<PREP_BLOCKS, 512, 0, stream>>>(x, W0, W1, W2, b0, b1, b2, ws);
    edge_kernel<<<N_EDGES / 256, 512, 0, stream>>>(ei, ws, out);
}